// Round 1
// baseline (26.150 us; speedup 1.0000x reference)
//
#include <hip/hip_runtime.h>
#include <math.h>

// Problem constants (from setup_inputs): B=4, L=2048, C=3, N_RES=256.
#define BB 4
#define LL 2048

// Mask layout sniffing: the harness's device representation of a jnp.bool_
// input is ambiguous (1-byte bool, int32, or float32). Detect from the first
// 256 bytes: int32 masks have all words in {0,1}; float32 masks in
// {0, 0x3F800000}; a random byte-bool buffer matches neither with
// probability ~2^-192.
__device__ __forceinline__ bool get_mask(const void* m, int layout, int idx) {
    if (layout == 1) return ((const int*)m)[idx] != 0;
    if (layout == 2) return ((const float*)m)[idx] != 0.0f;
    return ((const unsigned char*)m)[idx] != 0;
}

__global__ void pair_loss_kernel(const float* __restrict__ pred,
                                 const float* __restrict__ target,
                                 const void* __restrict__ mask,
                                 const int* __restrict__ res_idx,
                                 float* __restrict__ ws_sum,
                                 unsigned int* __restrict__ ws_cnt) {
    __shared__ int s_layout;
    __shared__ float s_sum[256];
    __shared__ unsigned int s_cnt[256];

    const int tid = threadIdx.x;

    if (tid == 0) {
        const int* w = (const int*)mask;
        bool all01 = true, allf = true;
        #pragma unroll 1
        for (int k = 0; k < 64; ++k) {
            int v = w[k];
            if (v != 0 && v != 1) all01 = false;
            if (v != 0 && v != 0x3F800000) allf = false;
        }
        s_layout = all01 ? 1 : (allf ? 2 : 0);
    }
    __syncthreads();
    const int layout = s_layout;

    const int blocks_per_batch = LL / 256;
    const int b = blockIdx.x / blocks_per_batch;
    const int i = (blockIdx.x % blocks_per_batch) * 256 + tid;
    const int base = b * LL;

    float lsum = 0.0f;
    unsigned int lcnt = 0;

    if (get_mask(mask, layout, base + i)) {
        const int r = res_idx[base + i];
        const float px = pred[(base + i) * 3 + 0];
        const float py = pred[(base + i) * 3 + 1];
        const float pz = pred[(base + i) * 3 + 2];
        const float tx = target[(base + i) * 3 + 0];
        const float ty = target[(base + i) * 3 + 1];
        const float tz = target[(base + i) * 3 + 2];

        // res_idx is sorted per batch -> same-residue partners of i with j < i
        // are contiguous immediately before i.
        for (int j = i - 1; j >= 0 && res_idx[base + j] == r; --j) {
            if (!get_mask(mask, layout, base + j)) continue;
            const float dpx = px - pred[(base + j) * 3 + 0];
            const float dpy = py - pred[(base + j) * 3 + 1];
            const float dpz = pz - pred[(base + j) * 3 + 2];
            const float dqx = tx - target[(base + j) * 3 + 0];
            const float dqy = ty - target[(base + j) * 3 + 1];
            const float dqz = tz - target[(base + j) * 3 + 2];
            const float dp = sqrtf(dpx * dpx + dpy * dpy + dpz * dpz);
            const float dq = sqrtf(dqx * dqx + dqy * dqy + dqz * dqz);
            const float diff = dq - dp;
            lsum += diff * diff;
            lcnt += 1;
        }
    }

    s_sum[tid] = lsum;
    s_cnt[tid] = lcnt;
    __syncthreads();
    for (int s = 128; s > 0; s >>= 1) {
        if (tid < s) {
            s_sum[tid] += s_sum[tid + s];
            s_cnt[tid] += s_cnt[tid + s];
        }
        __syncthreads();
    }
    if (tid == 0) {
        atomicAdd(&ws_sum[b], s_sum[0]);
        atomicAdd(&ws_cnt[b], s_cnt[0]);
    }
}

__global__ void finalize_kernel(const float* __restrict__ ws_sum,
                                const unsigned int* __restrict__ ws_cnt,
                                float* __restrict__ out) {
    const int b = threadIdx.x;
    if (b < BB) {
        const float n = (float)ws_cnt[b];
        out[b] = sqrtf(ws_sum[b] / (n + 1e-6f) + 1e-6f);
    }
}

extern "C" void kernel_launch(void* const* d_in, const int* in_sizes, int n_in,
                              void* d_out, int out_size, void* d_ws, size_t ws_size,
                              hipStream_t stream) {
    const float* pred = (const float*)d_in[0];
    const float* target = (const float*)d_in[1];
    const void* mask = d_in[2];
    const int* res_idx = (const int*)d_in[3];
    float* out = (float*)d_out;

    float* ws_sum = (float*)d_ws;
    unsigned int* ws_cnt = (unsigned int*)(ws_sum + BB);

    // Zero the accumulators every launch (harness poisons ws once, never
    // re-poisons between graph replays).
    hipMemsetAsync(d_ws, 0, BB * (sizeof(float) + sizeof(unsigned int)), stream);

    pair_loss_kernel<<<BB * (LL / 256), 256, 0, stream>>>(pred, target, mask,
                                                          res_idx, ws_sum, ws_cnt);
    finalize_kernel<<<1, 64, 0, stream>>>(ws_sum, ws_cnt, out);
}